// Round 6
// baseline (174.315 us; speedup 1.0000x reference)
//
#include <hip/hip_runtime.h>

// Involution: B=16, C=256, H=W=56, mid=64, GROUPS=16, GROUP_SIZE=16, K=3 (KK=9)
// All fp32. Output (16,256,56,56).
//
// This revision: NO LDS, NO BARRIERS anywhere. Both hot kernels are built
// from fully independent waves so L2/L3 latency is hidden by TLP + compiler
// load pipelining (vmcnt gates only vector data, lgkmcnt only scalar weights).
//   conv1     : block 256 (4 indep waves), x per-lane from global (L1-shared),
//               weights via wave-uniform s_load.
//   conv2_inv : block 64 = ONE wave = ONE group. t -> registers (ping-pong
//               chunks), w2 via s_load, 4-deep tap pipeline. Grid 12544 with
//               XCD-local remap (16 group-waves of a pixel chunk share an XCD).

#define Cn    256
#define MID   64
#define Hn    56
#define Wn    56
#define HW    3136
#define Bn    16
#define NPIX  (Bn * HW)       // 50176
#define CHW   (Cn * HW)
#define NKK   9
#define NG    16
#define GSZ   16
#define PXT   64              // pixels per chunk (49 chunks/batch, 784 total)
#define BN_EPS 1e-5f

// ---------------------------------------------------------------------------
// prep: w1f[c*64+o] = w1[o*256+c] * scale[o];  bias1[o] = beta[o]-mean[o]*scale[o]
// ---------------------------------------------------------------------------
__global__ __launch_bounds__(256) void prep_kernel(
    const float* __restrict__ w1,
    const float* __restrict__ gamma,
    const float* __restrict__ beta,
    const float* __restrict__ mean,
    const float* __restrict__ var,
    float* __restrict__ w1f,
    float* __restrict__ bias1) {
  int idx = blockIdx.x * 256 + threadIdx.x;
  if (idx < MID * Cn) {
    int c = idx >> 6;
    int o = idx & 63;
    float scale = gamma[o] / sqrtf(var[o] + BN_EPS);
    w1f[idx] = w1[o * Cn + c] * scale;
  } else if (idx < MID * Cn + MID) {
    int o = idx - MID * Cn;
    float scale = gamma[o] / sqrtf(var[o] + BN_EPS);
    bias1[o] = beta[o] - mean[o] * scale;
  }
}

// ---------------------------------------------------------------------------
// conv1: t[o][px] = relu(bias1[o] + sum_c x[b,c,px] * w1f[c*64+o])
// Block = 64 px x 32 outputs (grid 1568). Wave wv -> outputs oh*32+wv*8..+7.
// x: per-lane coalesced global loads (4 waves share cache lines via L1;
//    block slab = 16 KB, fits L1). NO LDS, NO barriers -> compiler pipelines
//    loads deep; vmcnt tracks x only, lgkmcnt tracks weight s_loads only.
// ---------------------------------------------------------------------------
__global__ __launch_bounds__(256) void conv1_kernel(
    const float* __restrict__ x,
    const float* __restrict__ w1f,
    const float* __restrict__ bias1,
    float* __restrict__ t) {
  const int tid = threadIdx.x;
  const int px  = tid & 63;
  const int wv  = __builtin_amdgcn_readfirstlane(tid >> 6);   // 0..3

  const int bid = blockIdx.x;
  const int pc  = bid >> 1;            // pixel chunk 0..783
  const int oh  = bid & 1;             // output half 0..1
  const int px0 = pc * PXT;
  const int b   = px0 / HW;
  const int hw0 = px0 - b * HW;
  const float* xb = x + (size_t)b * CHW + hw0 + px;   // per-lane base

  const float* wr0 = w1f + (oh << 5) + (wv << 3);     // wave-uniform

  float acc[8];
#pragma unroll
  for (int j = 0; j < 8; ++j) acc[j] = 0.0f;

  for (int c = 0; c < Cn; c += 8) {
    float xv[8];
#pragma unroll
    for (int i = 0; i < 8; ++i) xv[i] = xb[(size_t)(c + i) * HW];
#pragma unroll
    for (int i = 0; i < 8; ++i) {
      const float* wr = wr0 + ((c + i) << 6);          // uniform -> s_load x2
      const float4 wa = *(const float4*)(wr + 0);
      const float4 wb = *(const float4*)(wr + 4);
      acc[0] = fmaf(xv[i], wa.x, acc[0]);
      acc[1] = fmaf(xv[i], wa.y, acc[1]);
      acc[2] = fmaf(xv[i], wa.z, acc[2]);
      acc[3] = fmaf(xv[i], wa.w, acc[3]);
      acc[4] = fmaf(xv[i], wb.x, acc[4]);
      acc[5] = fmaf(xv[i], wb.y, acc[5]);
      acc[6] = fmaf(xv[i], wb.z, acc[6]);
      acc[7] = fmaf(xv[i], wb.w, acc[7]);
    }
  }

#pragma unroll
  for (int j = 0; j < 8; ++j) {
    const int o = (oh << 5) + (wv << 3) + j;
    t[(size_t)o * NPIX + px0 + px] = fmaxf(acc[j] + bias1[o], 0.0f);
  }
}

// ---------------------------------------------------------------------------
// conv2 + involution. Block = ONE wave (64 threads) = ONE group. Grid 12544.
// bid remap: r=bid&7, k=bid>>3, g=k&15, pc=(k>>4)*8+r  -> all 16 group-waves
// of a pixel chunk share bid%8 (same XCD) and sit 8 apart in dispatch order
// => t tile lands in that XCD's L2 once, hit by the other 15 waves.
// t: straight into registers, 16-float ping-pong chunks (static indexing).
// w2/b2: wave-uniform s_load (scalar pipe). Taps: 4-deep register pipeline.
// NO LDS, NO barriers -> every wave independent; TLP hides L2/L3 latency.
// ---------------------------------------------------------------------------
#define LOADCH(dst, ch)                                                   \
  {                                                                       \
    const float* _xp = xcg + (size_t)(ch) * HW;                           \
    _Pragma("unroll")                                                     \
    for (int kk = 0; kk < NKK; ++kk) dst[kk] = _xp[off[kk]];              \
  }
#define CONSUME(src, ch)                                                  \
  {                                                                       \
    float s0 = wk[0] * src[0];                                            \
    float s1 = wk[1] * src[1];                                            \
    float s2 = wk[2] * src[2];                                            \
    s0 = fmaf(wk[3], src[3], s0);                                         \
    s1 = fmaf(wk[4], src[4], s1);                                         \
    s2 = fmaf(wk[5], src[5], s2);                                         \
    s0 = fmaf(wk[6], src[6], s0);                                         \
    s1 = fmaf(wk[7], src[7], s1);                                         \
    s2 = fmaf(wk[8], src[8], s2);                                         \
    ob[(size_t)(ch) * HW] = s0 + s1 + s2;                                 \
  }
// conv2 partial: a[kk] += sum over o4..o4+3 of w2 x t, for one 16-o chunk
#define C2CHUNK(CUR, CH)                                                  \
  {                                                                       \
    _Pragma("unroll")                                                     \
    for (int o4 = 0; o4 < 16; o4 += 4) {                                  \
      const int ob_ = (CH) * 16 + o4;                                     \
      _Pragma("unroll")                                                   \
      for (int kk = 0; kk < NKK; ++kk) {                                  \
        const float4 w4 = *(const float4*)(wg + (kk << 6) + ob_);         \
        a[kk] = fmaf(CUR[o4 + 3], w4.w,                                   \
                fmaf(CUR[o4 + 2], w4.z,                                   \
                fmaf(CUR[o4 + 1], w4.y,                                   \
                fmaf(CUR[o4 + 0], w4.x, a[kk]))));                        \
      }                                                                   \
    }                                                                     \
  }

__global__ __launch_bounds__(64) void conv2_inv_kernel(
    const float* __restrict__ x,
    const float* __restrict__ t,
    const float* __restrict__ w2,
    const float* __restrict__ b2,
    float* __restrict__ out) {
  const int px  = threadIdx.x;         // 0..63

  const int bid = blockIdx.x;
  const int r   = bid & 7;
  const int k   = bid >> 3;
  const int g   = k & 15;              // group (wave-uniform)
  const int pc  = ((k >> 4) << 3) + r; // pixel chunk 0..783

  const int px0 = pc * PXT;
  const int b   = px0 / HW;
  const int hw0 = px0 - b * HW;

  const float* tb = t + px0 + px;      // t[o][px]: stride NPIX

  // ---- issue t chunk 0 (16 coalesced loads, L2/L3-hot) ----
  float tvA[16], tvB[16];
#pragma unroll
  for (int i = 0; i < 16; ++i) tvA[i] = tb[(size_t)i * NPIX];

  // ---- tap geometry (VALU, overlaps loads) ----
  const int hw = hw0 + px;
  const int h  = hw / Wn;
  const int w  = hw - h * Wn;

  int off[NKK];
  unsigned vmask = 0;
#pragma unroll
  for (int kk = 0; kk < NKK; ++kk) {
    const int di  = kk / 3 - 1;
    const int dj  = kk % 3 - 1;
    const int h2  = h + di;
    const int w2v = w + dj;
    const bool valid = ((unsigned)h2 < (unsigned)Hn) && ((unsigned)w2v < (unsigned)Wn);
    off[kk] = valid ? (h2 * Wn + w2v) : hw;
    vmask |= (valid ? 1u : 0u) << kk;
  }

  // ---- conv2: a[9] over 4 register chunks of t (ping-pong, static idx) ----
  float a[NKK];
#pragma unroll
  for (int kk = 0; kk < NKK; ++kk) a[kk] = b2[g * NKK + kk];   // uniform s_load

  const float* wg = w2 + (size_t)g * (NKK * MID);              // uniform base

#pragma unroll
  for (int i = 0; i < 16; ++i) tvB[i] = tb[(size_t)(16 + i) * NPIX];
  C2CHUNK(tvA, 0)
#pragma unroll
  for (int i = 0; i < 16; ++i) tvA[i] = tb[(size_t)(32 + i) * NPIX];
  C2CHUNK(tvB, 1)
#pragma unroll
  for (int i = 0; i < 16; ++i) tvB[i] = tb[(size_t)(48 + i) * NPIX];
  C2CHUNK(tvA, 2)
  C2CHUNK(tvB, 3)

  float wk[NKK];
#pragma unroll
  for (int kk = 0; kk < NKK; ++kk)
    wk[kk] = ((vmask >> kk) & 1u) ? a[kk] : 0.0f;

  // ---- involution: 4-deep software pipeline over 16 channels ----
  const float* xcg = x + (size_t)b * CHW + (size_t)(g * GSZ) * HW;
  float* ob = out + (size_t)b * CHW + (size_t)(g * GSZ) * HW + hw;

  float p0[NKK], p1[NKK], p2[NKK], p3[NKK];
  LOADCH(p0, 0)
  LOADCH(p1, 1)
  LOADCH(p2, 2)
  LOADCH(p3, 3)

  CONSUME(p0, 0)  LOADCH(p0, 4)
  CONSUME(p1, 1)  LOADCH(p1, 5)
  CONSUME(p2, 2)  LOADCH(p2, 6)
  CONSUME(p3, 3)  LOADCH(p3, 7)
  CONSUME(p0, 4)  LOADCH(p0, 8)
  CONSUME(p1, 5)  LOADCH(p1, 9)
  CONSUME(p2, 6)  LOADCH(p2, 10)
  CONSUME(p3, 7)  LOADCH(p3, 11)
  CONSUME(p0, 8)  LOADCH(p0, 12)
  CONSUME(p1, 9)  LOADCH(p1, 13)
  CONSUME(p2, 10) LOADCH(p2, 14)
  CONSUME(p3, 11) LOADCH(p3, 15)
  CONSUME(p0, 12)
  CONSUME(p1, 13)
  CONSUME(p2, 14)
  CONSUME(p3, 15)
}

// ---------------------------------------------------------------------------
extern "C" void kernel_launch(void* const* d_in, const int* in_sizes, int n_in,
                              void* d_out, int out_size, void* d_ws, size_t ws_size,
                              hipStream_t stream) {
  const float* x     = (const float*)d_in[0];
  const float* w1    = (const float*)d_in[1];
  const float* gamma = (const float*)d_in[2];
  const float* beta  = (const float*)d_in[3];
  const float* mean  = (const float*)d_in[4];
  const float* var   = (const float*)d_in[5];
  const float* w2    = (const float*)d_in[6];
  const float* b2    = (const float*)d_in[7];
  float* out = (float*)d_out;

  // workspace: t (64 x 50176 fp32 = 12.85 MB) | w1f (64 KB) | bias1 (256 B)
  char* ws = (char*)d_ws;
  float* t     = (float*)ws;
  float* w1f   = (float*)(ws + (size_t)MID * NPIX * 4);
  float* bias1 = (float*)(ws + (size_t)MID * NPIX * 4 + (size_t)MID * Cn * 4);

  prep_kernel<<<(MID * Cn + MID + 255) / 256, 256, 0, stream>>>(
      w1, gamma, beta, mean, var, w1f, bias1);
  conv1_kernel<<<NPIX / PXT * 2, 256, 0, stream>>>(x, w1f, bias1, t);
  conv2_inv_kernel<<<NPIX / PXT * NG, 64, 0, stream>>>(x, t, w2, b2, out);
}

// Round 8
// 165.932 us; speedup vs baseline: 1.0505x; 1.0505x over previous
//
#include <hip/hip_runtime.h>

// Involution: B=16, C=256, H=W=56, mid=64, GROUPS=16, GROUP_SIZE=16, K=3 (KK=9)
// All fp32. Output (16,256,56,56).
//
// This revision:
//  conv1     : round-5 triple-buffer structure, OSPLIT 2->4 (grid 3136) with
//              XCD-local remap -> 2x resident waves to hide staging latency.
//  conv2_inv : round-5 structure + SRSRC buffer addressing for involution
//              taps/stores: per-lane voffset registers computed ONCE, channel
//              stride on scalar soffset -> ~480 addr-VALU/thread eliminated.
//              Invalid taps use HW bounds-check (OOB load returns 0) -> no
//              vmask/cndmask.  (b32 builtins + __amdgpu_buffer_rsrc_t.)

#define Cn    256
#define MID   64
#define Hn    56
#define Wn    56
#define HW    3136
#define Bn    16
#define NPIX  (Bn * HW)       // 50176
#define CHW   (Cn * HW)
#define NKK   9
#define NG    16
#define GSZ   16
#define PXT   64              // pixels per chunk (49 chunks/batch, 784 total)
#define BN_EPS 1e-5f

// async global->LDS: per-lane global src, wave-uniform LDS base + lane*size
#define GLOAD_LDS(src, dst, sz)                                                        \
  __builtin_amdgcn_global_load_lds(                                                    \
      (const __attribute__((address_space(1))) void*)(src),                            \
      (__attribute__((address_space(3))) void*)(dst), (sz), 0, 0)

// buffer resource: base, stride=0, num_records=bytes, word3=0x20000 (raw dword)
static __device__ __forceinline__ __amdgpu_buffer_rsrc_t
make_rsrc(const void* p, unsigned bytes) {
  return __builtin_amdgcn_make_buffer_rsrc((void*)p, (short)0, (int)bytes, 0x20000);
}

// ---------------------------------------------------------------------------
// prep: w1f[c*64+o] = w1[o*256+c] * scale[o];  bias1[o] = beta[o]-mean[o]*scale[o]
// ---------------------------------------------------------------------------
__global__ __launch_bounds__(256) void prep_kernel(
    const float* __restrict__ w1,
    const float* __restrict__ gamma,
    const float* __restrict__ beta,
    const float* __restrict__ mean,
    const float* __restrict__ var,
    float* __restrict__ w1f,
    float* __restrict__ bias1) {
  int idx = blockIdx.x * 256 + threadIdx.x;
  if (idx < MID * Cn) {
    int c = idx >> 6;
    int o = idx & 63;
    float scale = gamma[o] / sqrtf(var[o] + BN_EPS);
    w1f[idx] = w1[o * Cn + c] * scale;
  } else if (idx < MID * Cn + MID) {
    int o = idx - MID * Cn;
    float scale = gamma[o] / sqrtf(var[o] + BN_EPS);
    bias1[o] = beta[o] - mean[o] * scale;
  }
}

// ---------------------------------------------------------------------------
// conv1: t[o][px] = relu(bias1[o] + sum_c x[b,c,px] * w1f[c*64+o])
// Block = 64 px x 16 outputs (OSPLIT=4, grid 3136). Wave wv -> 4 outputs.
// bid remap: r=bid&7, k0=bid>>3, oq=k0&3, pc=(k0>>2)*8+r  -> the 4 output-
// quarter blocks of a pixel chunk share bid%8 (same XCD): x chunk fetched
// into that L2 once, re-read 3x from L2.
// x: 16-channel tiles in TRIPLE-buffered LDS (1 width-16 gload/wave/tile),
// counted vmcnt (never 0 in loop). Weights: wave-uniform s_load.
// ---------------------------------------------------------------------------
__global__ __launch_bounds__(256) void conv1_kernel(
    const float* __restrict__ x,
    const float* __restrict__ w1f,
    const float* __restrict__ bias1,
    float* __restrict__ t) {
  __shared__ __align__(16) float lx[3][16][PXT];   // 12 KB triple buffer

  const int tid = threadIdx.x;
  const int px  = tid & 63;
  const int wv  = __builtin_amdgcn_readfirstlane(tid >> 6);   // 0..3

  const int bid = blockIdx.x;
  const int r   = bid & 7;
  const int k0  = bid >> 3;
  const int oq  = k0 & 3;                // output quarter 0..3
  const int pc  = ((k0 >> 2) << 3) + r;  // pixel chunk 0..783
  const int px0 = pc * PXT;
  const int b   = px0 / HW;
  const int hw0 = px0 - b * HW;
  const float* xb = x + (size_t)b * CHW + hw0;

  const int rsub = px >> 4;            // 0..3
  const int csub = (px & 15) << 2;     // 0,4,..,60
  const int lrow = (wv << 2) + rsub;   // lane's row within the 16-row tile

  // prologue: issue tiles 0 and 1
  GLOAD_LDS(xb + (size_t)lrow * HW + csub, &lx[0][wv << 2][0], 16);
  GLOAD_LDS(xb + (size_t)(16 + lrow) * HW + csub, &lx[1][wv << 2][0], 16);

  float acc[4] = {0.0f, 0.0f, 0.0f, 0.0f};

  for (int k = 0; k < 16; ++k) {
    // wait own tile-k load only; tile k+1 stays outstanding. Each wave waits
    // its own vmcnt BEFORE the barrier -> after barrier all waves' k-loads done.
    if (k < 15) {
      asm volatile("s_waitcnt vmcnt(1)" ::: "memory");
    } else {
      asm volatile("s_waitcnt vmcnt(0)" ::: "memory");
    }
    __builtin_amdgcn_s_barrier();
    __builtin_amdgcn_sched_barrier(0);
    if (k < 14) {                      // issue tile k+2 (buf read at iter k-1;
      const int nb = (k + 2) % 3;      //  barrier proves all waves are past it)
      GLOAD_LDS(xb + (size_t)((k + 2) * 16 + lrow) * HW + csub,
                &lx[nb][wv << 2][0], 16);
    }
    const float* lxk = &lx[k % 3][0][0];
    const float* wr0 = w1f + (k << 10) + (oq << 4) + (wv << 2);
#pragma unroll
    for (int c = 0; c < 16; ++c) {
      const float xv = lxk[(c << 6) + px];
      const float4 wa = *(const float4*)(wr0 + (c << 6));   // uniform -> s_load
      acc[0] = fmaf(xv, wa.x, acc[0]);
      acc[1] = fmaf(xv, wa.y, acc[1]);
      acc[2] = fmaf(xv, wa.z, acc[2]);
      acc[3] = fmaf(xv, wa.w, acc[3]);
    }
  }

#pragma unroll
  for (int j = 0; j < 4; ++j) {
    const int o = (oq << 4) + (wv << 2) + j;
    t[(size_t)o * NPIX + px0 + px] = fmaxf(acc[j] + bias1[o], 0.0f);
  }
}

// ---------------------------------------------------------------------------
// conv2 + involution. Block = 64 px x ONE group-quad, grid 3136.
// bid decode: pc = (bid>>5)*8 + (bid&7), gq = (bid>>3)&3  -> all 4 quads of a
// pc share bid%8 (XCD-local t).
// Taps/stores: SRSRC buffer ops. voff[9] computed once (per-lane), channel
// offset cc*HW*4 rides soffset (scalar). Invalid taps -> huge voffset -> HW
// bounds check returns 0 (no vmask). 4-deep register pipeline, first 4
// channels issued before the staging barrier.
// ---------------------------------------------------------------------------
#define LOADCH(dst, ch)                                                   \
  {                                                                       \
    _Pragma("unroll")                                                     \
    for (int kk = 0; kk < NKK; ++kk)                                      \
      dst[kk] = __int_as_float(__builtin_amdgcn_raw_buffer_load_b32(      \
          xrs, voff[kk], (ch) * (HW * 4), 0));                            \
  }
#define CONSUME(src, ch)                                                  \
  {                                                                       \
    float s0 = wk[0] * src[0];                                            \
    float s1 = wk[1] * src[1];                                            \
    float s2 = wk[2] * src[2];                                            \
    s0 = fmaf(wk[3], src[3], s0);                                         \
    s1 = fmaf(wk[4], src[4], s1);                                         \
    s2 = fmaf(wk[5], src[5], s2);                                         \
    s0 = fmaf(wk[6], src[6], s0);                                         \
    s1 = fmaf(wk[7], src[7], s1);                                         \
    s2 = fmaf(wk[8], src[8], s2);                                         \
    __builtin_amdgcn_raw_buffer_store_b32(__float_as_int(s0 + s1 + s2),   \
                                          ors, hw4, (ch) * (HW * 4), 0); \
  }

__global__ __launch_bounds__(256, 4) void conv2_inv_kernel(
    const float* __restrict__ x,
    const float* __restrict__ t,
    const float* __restrict__ w2,
    const float* __restrict__ b2,
    float* __restrict__ out) {
  __shared__ __align__(16) float lt[MID][PXT];          // 16 KB

  const int tid = threadIdx.x;
  const int px  = tid & 63;
  const int wv  = __builtin_amdgcn_readfirstlane(tid >> 6);   // 0..3

  const int bid = blockIdx.x;
  const int pc  = ((bid >> 5) << 3) + (bid & 7);   // pixel chunk 0..783
  const int gq  = (bid >> 3) & 3;                  // group quad 0..3
  const int g   = (gq << 2) + wv;                  // wave's group (uniform)

  const int px0 = pc * PXT;
  const int b   = px0 / HW;
  const int hw0 = px0 - b * HW;

  const int rsub = px >> 4;
  const int csub = (px & 15) << 2;

  // ---- issue t-tile staging (async) ----
#pragma unroll
  for (int j = 0; j < 4; ++j) {
    const int r0 = (wv << 4) + (j << 2);
    GLOAD_LDS(t + (size_t)(r0 + rsub) * NPIX + px0 + csub, &lt[r0][0], 16);
  }

  // ---- buffer descriptors over this wave's group slab (wave-uniform) ----
  const __amdgpu_buffer_rsrc_t xrs =
      make_rsrc(x + (size_t)b * CHW + (size_t)(g * GSZ) * HW, GSZ * HW * 4);
  const __amdgpu_buffer_rsrc_t ors =
      make_rsrc(out + (size_t)b * CHW + (size_t)(g * GSZ) * HW, GSZ * HW * 4);

  // ---- tap geometry (VALU, overlaps staging). voff computed ONCE. ----
  const int hw = hw0 + px;
  const int h  = hw / Wn;
  const int w  = hw - h * Wn;
  const int hw4 = hw << 2;

  int voff[NKK];
#pragma unroll
  for (int kk = 0; kk < NKK; ++kk) {
    const int di  = kk / 3 - 1;
    const int dj  = kk % 3 - 1;
    const int h2  = h + di;
    const int w2v = w + dj;
    const bool valid = ((unsigned)h2 < (unsigned)Hn) && ((unsigned)w2v < (unsigned)Wn);
    voff[kk] = valid ? ((h2 * Wn + w2v) << 2) : 0x60000000;   // OOB -> loads 0
  }

  // ---- pre-issue first 4 channels' taps (complete under the barrier drain) ----
  float p0[NKK], p1[NKK], p2[NKK], p3[NKK];
  float wkdummy[1];  // silence unused warnings pattern (not used)
  (void)wkdummy;
  LOADCH(p0, 0)
  LOADCH(p1, 1)
  LOADCH(p2, 2)
  LOADCH(p3, 3)

  __syncthreads();

  // ---- conv2: per-pixel kernel weights for group g, in registers ----
  float a[NKK];
#pragma unroll
  for (int kk = 0; kk < NKK; ++kk) a[kk] = b2[g * NKK + kk];   // uniform s_load

  const float* wg = w2 + (size_t)g * (NKK * MID);              // uniform base
#pragma unroll 4
  for (int o4 = 0; o4 < MID; o4 += 4) {
    const float t0 = lt[o4 + 0][px];
    const float t1 = lt[o4 + 1][px];
    const float t2 = lt[o4 + 2][px];
    const float t3 = lt[o4 + 3][px];
#pragma unroll
    for (int kk = 0; kk < NKK; ++kk) {
      const float4 w4 = *(const float4*)(wg + (kk << 6) + o4); // scalar pipe
      a[kk] = fmaf(t3, w4.w, fmaf(t2, w4.z, fmaf(t1, w4.y, fmaf(t0, w4.x, a[kk]))));
    }
  }

  const float* wk = a;   // OOB taps already load 0 -> no masking needed

  // ---- involution: 4-deep software pipeline over 16 channels ----
  CONSUME(p0, 0)  LOADCH(p0, 4)
  CONSUME(p1, 1)  LOADCH(p1, 5)
  CONSUME(p2, 2)  LOADCH(p2, 6)
  CONSUME(p3, 3)  LOADCH(p3, 7)
  CONSUME(p0, 4)  LOADCH(p0, 8)
  CONSUME(p1, 5)  LOADCH(p1, 9)
  CONSUME(p2, 6)  LOADCH(p2, 10)
  CONSUME(p3, 7)  LOADCH(p3, 11)
  CONSUME(p0, 8)  LOADCH(p0, 12)
  CONSUME(p1, 9)  LOADCH(p1, 13)
  CONSUME(p2, 10) LOADCH(p2, 14)
  CONSUME(p3, 11) LOADCH(p3, 15)
  CONSUME(p0, 12)
  CONSUME(p1, 13)
  CONSUME(p2, 14)
  CONSUME(p3, 15)
}

// ---------------------------------------------------------------------------
extern "C" void kernel_launch(void* const* d_in, const int* in_sizes, int n_in,
                              void* d_out, int out_size, void* d_ws, size_t ws_size,
                              hipStream_t stream) {
  const float* x     = (const float*)d_in[0];
  const float* w1    = (const float*)d_in[1];
  const float* gamma = (const float*)d_in[2];
  const float* beta  = (const float*)d_in[3];
  const float* mean  = (const float*)d_in[4];
  const float* var   = (const float*)d_in[5];
  const float* w2    = (const float*)d_in[6];
  const float* b2    = (const float*)d_in[7];
  float* out = (float*)d_out;

  // workspace: t (64 x 50176 fp32 = 12.85 MB) | w1f (64 KB) | bias1 (256 B)
  char* ws = (char*)d_ws;
  float* t     = (float*)ws;
  float* w1f   = (float*)(ws + (size_t)MID * NPIX * 4);
  float* bias1 = (float*)(ws + (size_t)MID * NPIX * 4 + (size_t)MID * Cn * 4);

  prep_kernel<<<(MID * Cn + MID + 255) / 256, 256, 0, stream>>>(
      w1, gamma, beta, mean, var, w1f, bias1);
  conv1_kernel<<<NPIX / PXT * 4, 256, 0, stream>>>(x, w1f, bias1, t);
  conv2_inv_kernel<<<NPIX / PXT * 4, 256, 0, stream>>>(x, t, w2, b2, out);
}

// Round 10
// 159.341 us; speedup vs baseline: 1.0940x; 1.0414x over previous
//
#include <hip/hip_runtime.h>

// Involution: B=16, C=256, H=W=56, mid=64, GROUPS=16, GROUP_SIZE=16, K=3 (KK=9)
// All fp32. Output (16,256,56,56).
//
// This revision (resubmit of round-8 kernel; previous bench died to a
// container-infrastructure failure, not a kernel error):
//  conv1     : acc[16] shape (1 ds_read feeds 16 FMAs -> LDS pipe off the
//              critical path) + triple-buffered staging with counted
//              s_waitcnt vmcnt(1) + raw s_barrier (loads in flight across
//              barriers). Grid 784, pc == bid (XCD pc%8 matches conv2 remap).
//  conv2_inv : round-5 tap code (plain pointers, __restrict__ aliasing
//              preserved -> loads hoist over stores) + results batched in
//              res[16], all 16 stores at the end.

#define Cn    256
#define MID   64
#define Hn    56
#define Wn    56
#define HW    3136
#define Bn    16
#define NPIX  (Bn * HW)       // 50176
#define CHW   (Cn * HW)
#define NKK   9
#define NG    16
#define GSZ   16
#define PXT   64              // pixels per chunk (49 chunks/batch, 784 total)
#define BN_EPS 1e-5f

// async global->LDS: per-lane global src, wave-uniform LDS base + lane*size
#define GLOAD_LDS(src, dst, sz)                                                        \
  __builtin_amdgcn_global_load_lds(                                                    \
      (const __attribute__((address_space(1))) void*)(src),                            \
      (__attribute__((address_space(3))) void*)(dst), (sz), 0, 0)

// ---------------------------------------------------------------------------
// prep: w1f[c*64+o] = w1[o*256+c] * scale[o];  bias1[o] = beta[o]-mean[o]*scale[o]
// ---------------------------------------------------------------------------
__global__ __launch_bounds__(256) void prep_kernel(
    const float* __restrict__ w1,
    const float* __restrict__ gamma,
    const float* __restrict__ beta,
    const float* __restrict__ mean,
    const float* __restrict__ var,
    float* __restrict__ w1f,
    float* __restrict__ bias1) {
  int idx = blockIdx.x * 256 + threadIdx.x;
  if (idx < MID * Cn) {
    int c = idx >> 6;
    int o = idx & 63;
    float scale = gamma[o] / sqrtf(var[o] + BN_EPS);
    w1f[idx] = w1[o * Cn + c] * scale;
  } else if (idx < MID * Cn + MID) {
    int o = idx - MID * Cn;
    float scale = gamma[o] / sqrtf(var[o] + BN_EPS);
    bias1[o] = beta[o] - mean[o] * scale;
  }
}

// ---------------------------------------------------------------------------
// conv1: t[o][px] = relu(bias1[o] + sum_c x[b,c,px] * w1f[c*64+o])
// Block = 64 px x ALL 64 outputs (grid 784). Wave wv -> outputs wv*16..+15.
// Per c: 1 ds_read_b32 (x) + 4 wave-uniform s_load_dwordx4 (weights) + 16 FMA
//   -> ds:FMA = 1:16, LDS pipe ~1.5K cy/wave vs VALU ~8K cy/wave.
// x tiles (16 c x 64 px = 4 KB): TRIPLE-buffered, 1 width-16 global_load_lds
// per wave per tile, counted vmcnt(1) -> next tile's load spans the barrier.
// ---------------------------------------------------------------------------
__global__ __launch_bounds__(256) void conv1_kernel(
    const float* __restrict__ x,
    const float* __restrict__ w1f,
    const float* __restrict__ bias1,
    float* __restrict__ t) {
  __shared__ __align__(16) float lx[3][16][PXT];   // 12 KB triple buffer

  const int tid = threadIdx.x;
  const int px  = tid & 63;
  const int wv  = __builtin_amdgcn_readfirstlane(tid >> 6);   // 0..3

  const int bid = blockIdx.x;          // pc == bid; XCD = bid%8 (matches conv2)
  const int px0 = bid * PXT;
  const int b   = px0 / HW;
  const int hw0 = px0 - b * HW;
  const float* xb = x + (size_t)b * CHW + hw0;

  const int rsub = px >> 4;            // 0..3
  const int csub = (px & 15) << 2;     // 0,4,..,60
  const int lrow = (wv << 2) + rsub;   // lane's row within the 16-row tile

  // prologue: issue tiles 0 and 1 (stay in flight into the loop)
  GLOAD_LDS(xb + (size_t)lrow * HW + csub, &lx[0][wv << 2][0], 16);
  GLOAD_LDS(xb + (size_t)(16 + lrow) * HW + csub, &lx[1][wv << 2][0], 16);

  float acc[16];
#pragma unroll
  for (int j = 0; j < 16; ++j) acc[j] = 0.0f;

  for (int k = 0; k < 16; ++k) {
    // wait tile k only; tile k+1's load stays outstanding (counted vmcnt).
    if (k < 15) {
      asm volatile("s_waitcnt vmcnt(1)" ::: "memory");
    } else {
      asm volatile("s_waitcnt vmcnt(0)" ::: "memory");
    }
    __builtin_amdgcn_s_barrier();      // all waves' tile-k loads done
    __builtin_amdgcn_sched_barrier(0); // no ds_read hoisting above the wait
    if (k < 14) {                      // issue tile k+2 (its buffer was last
      const int nb = (k + 2) % 3;      //  read at iter k-1; barrier proves done)
      GLOAD_LDS(xb + (size_t)((k + 2) * 16 + lrow) * HW + csub,
                &lx[nb][wv << 2][0], 16);
    }
    const float* lxk = &lx[k % 3][0][0];
    const float* wr0 = w1f + (k << 10) + (wv << 4);
#pragma unroll
    for (int c = 0; c < 16; ++c) {
      const float xv = lxk[(c << 6) + px];
      const float* wr = wr0 + (c << 6);            // wave-uniform -> s_load x4
      const float4 wa = *(const float4*)(wr + 0);
      const float4 wb = *(const float4*)(wr + 4);
      const float4 wc = *(const float4*)(wr + 8);
      const float4 wd = *(const float4*)(wr + 12);
      acc[0]  = fmaf(xv, wa.x, acc[0]);
      acc[1]  = fmaf(xv, wa.y, acc[1]);
      acc[2]  = fmaf(xv, wa.z, acc[2]);
      acc[3]  = fmaf(xv, wa.w, acc[3]);
      acc[4]  = fmaf(xv, wb.x, acc[4]);
      acc[5]  = fmaf(xv, wb.y, acc[5]);
      acc[6]  = fmaf(xv, wb.z, acc[6]);
      acc[7]  = fmaf(xv, wb.w, acc[7]);
      acc[8]  = fmaf(xv, wc.x, acc[8]);
      acc[9]  = fmaf(xv, wc.y, acc[9]);
      acc[10] = fmaf(xv, wc.z, acc[10]);
      acc[11] = fmaf(xv, wc.w, acc[11]);
      acc[12] = fmaf(xv, wd.x, acc[12]);
      acc[13] = fmaf(xv, wd.y, acc[13]);
      acc[14] = fmaf(xv, wd.z, acc[14]);
      acc[15] = fmaf(xv, wd.w, acc[15]);
    }
  }

#pragma unroll
  for (int j = 0; j < 16; ++j) {
    const int o = (wv << 4) + j;
    t[(size_t)o * NPIX + px0 + px] = fmaxf(acc[j] + bias1[o], 0.0f);
  }
}

// ---------------------------------------------------------------------------
// conv2 + involution. Block = 64 px x ONE group-quad, grid 3136.
// bid decode: pc = (bid>>5)*8 + (bid&7), gq = (bid>>3)&3  -> all 4 quads of a
// pc share bid%8 (XCD-local t, same XCD as the conv1 writer block).
// Taps: plain __restrict__ pointer loads (compiler hoists freely), 4-deep
// register pipeline, first 4 channels issued before the staging barrier.
// Results accumulate in res[16]; ALL stores batched at the end (no store
// between a tap load and its consumer).
// ---------------------------------------------------------------------------
#define LOADCH(dst, ch)                                                   \
  {                                                                       \
    const float* _xp = xcg + (size_t)(ch) * HW;                           \
    _Pragma("unroll")                                                     \
    for (int kk = 0; kk < NKK; ++kk) dst[kk] = _xp[off[kk]];              \
  }
#define CONSUME(src, ch)                                                  \
  {                                                                       \
    float s0 = wk[0] * src[0];                                            \
    float s1 = wk[1] * src[1];                                            \
    float s2 = wk[2] * src[2];                                            \
    s0 = fmaf(wk[3], src[3], s0);                                         \
    s1 = fmaf(wk[4], src[4], s1);                                         \
    s2 = fmaf(wk[5], src[5], s2);                                         \
    s0 = fmaf(wk[6], src[6], s0);                                         \
    s1 = fmaf(wk[7], src[7], s1);                                         \
    s2 = fmaf(wk[8], src[8], s2);                                         \
    res[ch] = s0 + s1 + s2;                                               \
  }

__global__ __launch_bounds__(256, 4) void conv2_inv_kernel(
    const float* __restrict__ x,
    const float* __restrict__ t,
    const float* __restrict__ w2,
    const float* __restrict__ b2,
    float* __restrict__ out) {
  __shared__ __align__(16) float lt[MID][PXT];          // 16 KB

  const int tid = threadIdx.x;
  const int px  = tid & 63;
  const int wv  = __builtin_amdgcn_readfirstlane(tid >> 6);   // 0..3

  const int bid = blockIdx.x;
  const int pc  = ((bid >> 5) << 3) + (bid & 7);   // pixel chunk 0..783
  const int gq  = (bid >> 3) & 3;                  // group quad 0..3
  const int g   = (gq << 2) + wv;                  // wave's group (uniform)

  const int px0 = pc * PXT;
  const int b   = px0 / HW;
  const int hw0 = px0 - b * HW;

  const int rsub = px >> 4;
  const int csub = (px & 15) << 2;

  // ---- issue t-tile staging (async) ----
#pragma unroll
  for (int j = 0; j < 4; ++j) {
    const int r0 = (wv << 4) + (j << 2);
    GLOAD_LDS(t + (size_t)(r0 + rsub) * NPIX + px0 + csub, &lt[r0][0], 16);
  }

  // ---- tap geometry (pure VALU, overlaps staging) ----
  const int hw = hw0 + px;
  const int h  = hw / Wn;
  const int w  = hw - h * Wn;

  int off[NKK];
  unsigned vmask = 0;
#pragma unroll
  for (int kk = 0; kk < NKK; ++kk) {
    const int di  = kk / 3 - 1;
    const int dj  = kk % 3 - 1;
    const int h2  = h + di;
    const int w2v = w + dj;
    const bool valid = ((unsigned)h2 < (unsigned)Hn) && ((unsigned)w2v < (unsigned)Wn);
    off[kk] = valid ? (h2 * Wn + w2v) : hw;
    vmask |= (valid ? 1u : 0u) << kk;
  }

  // ---- pre-issue first 4 channels' taps (complete under the barrier drain) ----
  const float* xcg = x + (size_t)b * CHW + (size_t)(g * GSZ) * HW;
  float p0[NKK], p1[NKK], p2[NKK], p3[NKK];
  LOADCH(p0, 0)
  LOADCH(p1, 1)
  LOADCH(p2, 2)
  LOADCH(p3, 3)

  __syncthreads();

  // ---- conv2: per-pixel kernel weights for group g, in registers ----
  float a[NKK];
#pragma unroll
  for (int kk = 0; kk < NKK; ++kk) a[kk] = b2[g * NKK + kk];   // uniform s_load

  const float* wg = w2 + (size_t)g * (NKK * MID);              // uniform base
#pragma unroll 4
  for (int o4 = 0; o4 < MID; o4 += 4) {
    const float t0 = lt[o4 + 0][px];
    const float t1 = lt[o4 + 1][px];
    const float t2 = lt[o4 + 2][px];
    const float t3 = lt[o4 + 3][px];
#pragma unroll
    for (int kk = 0; kk < NKK; ++kk) {
      const float4 w4 = *(const float4*)(wg + (kk << 6) + o4); // scalar pipe
      a[kk] = fmaf(t3, w4.w, fmaf(t2, w4.z, fmaf(t1, w4.y, fmaf(t0, w4.x, a[kk]))));
    }
  }

  float wk[NKK];
#pragma unroll
  for (int kk = 0; kk < NKK; ++kk)
    wk[kk] = ((vmask >> kk) & 1u) ? a[kk] : 0.0f;

  // ---- involution: 4-deep pipeline, results to registers ----
  float res[GSZ];

  CONSUME(p0, 0)  LOADCH(p0, 4)
  CONSUME(p1, 1)  LOADCH(p1, 5)
  CONSUME(p2, 2)  LOADCH(p2, 6)
  CONSUME(p3, 3)  LOADCH(p3, 7)
  CONSUME(p0, 4)  LOADCH(p0, 8)
  CONSUME(p1, 5)  LOADCH(p1, 9)
  CONSUME(p2, 6)  LOADCH(p2, 10)
  CONSUME(p3, 7)  LOADCH(p3, 11)
  CONSUME(p0, 8)  LOADCH(p0, 12)
  CONSUME(p1, 9)  LOADCH(p1, 13)
  CONSUME(p2, 10) LOADCH(p2, 14)
  CONSUME(p3, 11) LOADCH(p3, 15)
  CONSUME(p0, 12)
  CONSUME(p1, 13)
  CONSUME(p2, 14)
  CONSUME(p3, 15)

  // ---- batched stores (coalesced across lanes) ----
  float* ob = out + (size_t)b * CHW + (size_t)(g * GSZ) * HW + hw;
#pragma unroll
  for (int cc = 0; cc < GSZ; ++cc)
    ob[(size_t)cc * HW] = res[cc];
}

// ---------------------------------------------------------------------------
extern "C" void kernel_launch(void* const* d_in, const int* in_sizes, int n_in,
                              void* d_out, int out_size, void* d_ws, size_t ws_size,
                              hipStream_t stream) {
  const float* x     = (const float*)d_in[0];
  const float* w1    = (const float*)d_in[1];
  const float* gamma = (const float*)d_in[2];
  const float* beta  = (const float*)d_in[3];
  const float* mean  = (const float*)d_in[4];
  const float* var   = (const float*)d_in[5];
  const float* w2    = (const float*)d_in[6];
  const float* b2    = (const float*)d_in[7];
  float* out = (float*)d_out;

  // workspace: t (64 x 50176 fp32 = 12.85 MB) | w1f (64 KB) | bias1 (256 B)
  char* ws = (char*)d_ws;
  float* t     = (float*)ws;
  float* w1f   = (float*)(ws + (size_t)MID * NPIX * 4);
  float* bias1 = (float*)(ws + (size_t)MID * NPIX * 4 + (size_t)MID * Cn * 4);

  prep_kernel<<<(MID * Cn + MID + 255) / 256, 256, 0, stream>>>(
      w1, gamma, beta, mean, var, w1f, bias1);
  conv1_kernel<<<NPIX / PXT, 256, 0, stream>>>(x, w1f, bias1, t);
  conv2_inv_kernel<<<NPIX / PXT * 4, 256, 0, stream>>>(x, t, w2, b2, out);
}